// Round 1
// baseline (905.538 us; speedup 1.0000x reference)
//
#include <hip/hip_runtime.h>
#include <hip/hip_bf16.h>

#define NEG_INF -1000000000.0f

typedef __attribute__((ext_vector_type(8))) short bf16x8;
typedef __attribute__((ext_vector_type(4))) float f32x4;

__device__ __forceinline__ unsigned short f2bf(float f) {
    unsigned int u = __float_as_uint(f);
    u += 0x7FFFu + ((u >> 16) & 1u);
    return (unsigned short)(u >> 16);
}

// BT-form GEMM: C[m][n] = sum_k A[m][k] * B[n][k]   (A:[M,K], B:[N,K] row-major)
// AF32/BF32: input dtype is fp32 (convert to bf16 during staging) else bf16.
// EPI: 0 = projection (bf16 out, +bias, *scale, optional transposed store)
//      1 = scores (fp32 out, mask applied per column)
//      2 = plain fp32 out
template<bool AF32, bool BF32, int EPI, bool TRANS>
__global__ __launch_bounds__(256)
void gemm_bt(const void* __restrict__ Ap, const void* __restrict__ Bp,
             void* __restrict__ Cp, const float* __restrict__ bias,
             const int* __restrict__ mask,
             int M, int N, int K, long lda, long ldb, long ldc,
             long batchA, long batchB, long batchC, float scale)
{
    __shared__ unsigned short As[128][72];   // 64 + 8 pad (breaks 128B-stride bank conflict)
    __shared__ unsigned short Bs[128][72];

    const int t    = threadIdx.x;
    const int bm   = blockIdx.x * 128;
    const int bn   = blockIdx.y * 128;
    const int bz   = blockIdx.z;

    const int sx   = t & 15;        // staging: col group (4 elems)
    const int sy   = t >> 4;        // staging: row within pass
    const int lane = t & 63;
    const int w    = t >> 6;        // wave 0..3 -> 2x2 of 64x64
    const int wm   = (w >> 1) * 64;
    const int wn   = (w & 1) * 64;
    const int lr   = lane & 15;
    const int lk8  = (lane >> 4) * 8;

    const size_t aoff = (size_t)bz * (size_t)batchA;
    const size_t boff = (size_t)bz * (size_t)batchB;
    const size_t coff = (size_t)bz * (size_t)batchC;

    f32x4 acc[4][4];
#pragma unroll
    for (int i = 0; i < 4; ++i)
#pragma unroll
        for (int j = 0; j < 4; ++j)
            acc[i][j] = f32x4{0.f, 0.f, 0.f, 0.f};

    for (int kt = 0; kt < K; kt += 64) {
#pragma unroll
        for (int p = 0; p < 8; ++p) {
            const int row = p * 16 + sy;
            // ---- stage A tile ----
            if (AF32) {
                const float* ap = (const float*)Ap + aoff + (size_t)(bm + row) * lda + kt + sx * 4;
                const float4 v = *(const float4*)ap;
                ushort4 wv;
                wv.x = f2bf(v.x); wv.y = f2bf(v.y); wv.z = f2bf(v.z); wv.w = f2bf(v.w);
                *(ushort4*)&As[row][sx * 4] = wv;
            } else {
                const unsigned short* ap = (const unsigned short*)Ap + aoff + (size_t)(bm + row) * lda + kt + sx * 4;
                *(ushort4*)&As[row][sx * 4] = *(const ushort4*)ap;
            }
            // ---- stage B tile ----
            if (BF32) {
                const float* bp = (const float*)Bp + boff + (size_t)(bn + row) * ldb + kt + sx * 4;
                const float4 v = *(const float4*)bp;
                ushort4 wv;
                wv.x = f2bf(v.x); wv.y = f2bf(v.y); wv.z = f2bf(v.z); wv.w = f2bf(v.w);
                *(ushort4*)&Bs[row][sx * 4] = wv;
            } else {
                const unsigned short* bp = (const unsigned short*)Bp + boff + (size_t)(bn + row) * ldb + kt + sx * 4;
                *(ushort4*)&Bs[row][sx * 4] = *(const ushort4*)bp;
            }
        }
        __syncthreads();

#pragma unroll
        for (int kk = 0; kk < 2; ++kk) {
            bf16x8 af[4], bfr[4];
#pragma unroll
            for (int i = 0; i < 4; ++i)
                af[i] = *(const bf16x8*)&As[wm + i * 16 + lr][kk * 32 + lk8];
#pragma unroll
            for (int i = 0; i < 4; ++i)
                bfr[i] = *(const bf16x8*)&Bs[wn + i * 16 + lr][kk * 32 + lk8];
#pragma unroll
            for (int i = 0; i < 4; ++i)
#pragma unroll
                for (int j = 0; j < 4; ++j)
                    acc[i][j] = __builtin_amdgcn_mfma_f32_16x16x32_bf16(af[i], bfr[j], acc[i][j], 0, 0, 0);
        }
        __syncthreads();
    }

    // ---- epilogue ----  C/D layout: col = lane&15, row = (lane>>4)*4 + reg
    const int r0 = (lane >> 4) * 4;
#pragma unroll
    for (int i = 0; i < 4; ++i) {
#pragma unroll
        for (int j = 0; j < 4; ++j) {
            const int gcol = bn + wn + j * 16 + lr;
            if (EPI == 0) {
                const float bv = bias[gcol];
                if (TRANS) {
                    // store transposed: C_t[b][n][s], m = b*2048 + s
                    const int m0 = bm + wm + i * 16 + r0;
                    const int bb = m0 >> 11;
                    const int s0 = m0 & 2047;
                    ushort4 wv;
                    wv.x = f2bf((acc[i][j][0] + bv) * scale);
                    wv.y = f2bf((acc[i][j][1] + bv) * scale);
                    wv.z = f2bf((acc[i][j][2] + bv) * scale);
                    wv.w = f2bf((acc[i][j][3] + bv) * scale);
                    *(ushort4*)((unsigned short*)Cp + (size_t)bb * (1024 * 2048)
                                + (size_t)gcol * 2048 + s0) = wv;
                } else {
#pragma unroll
                    for (int r = 0; r < 4; ++r) {
                        const int grow = bm + wm + i * 16 + r0 + r;
                        ((unsigned short*)Cp)[(size_t)grow * ldc + gcol] =
                            f2bf((acc[i][j][r] + bv) * scale);
                    }
                }
            } else if (EPI == 1) {
                const int mv = mask[(size_t)bz * 2048 + gcol];
#pragma unroll
                for (int r = 0; r < 4; ++r) {
                    const int grow = bm + wm + i * 16 + r0 + r;
                    float v = acc[i][j][r];
                    if (mv == 0) v = NEG_INF;
                    ((float*)Cp)[coff + (size_t)grow * ldc + gcol] = v;
                }
            } else {
#pragma unroll
                for (int r = 0; r < 4; ++r) {
                    const int grow = bm + wm + i * 16 + r0 + r;
                    ((float*)Cp)[coff + (size_t)grow * ldc + gcol] = acc[i][j][r];
                }
            }
        }
    }
}

// Row softmax over 2048 fp32 scores; writes P as bf16 in-place into the low
// half of the row's storage (row byte stride stays 8192 B -> 4096 bf16 elems).
__global__ __launch_bounds__(256)
void softmax_rows(float* __restrict__ S)
{
    const size_t row = blockIdx.x;
    float* sr = S + row * 2048;
    const int t = threadIdx.x;

    const float4 v0 = *(const float4*)&sr[t * 8];
    const float4 v1 = *(const float4*)&sr[t * 8 + 4];

    float m = fmaxf(fmaxf(fmaxf(v0.x, v0.y), fmaxf(v0.z, v0.w)),
                    fmaxf(fmaxf(v1.x, v1.y), fmaxf(v1.z, v1.w)));

    __shared__ float red[256];
    red[t] = m;
    __syncthreads();
    for (int s = 128; s > 0; s >>= 1) {
        if (t < s) red[t] = fmaxf(red[t], red[t + s]);
        __syncthreads();
    }
    const float mx = red[0];
    __syncthreads();

    float e[8];
    e[0] = __expf(v0.x - mx); e[1] = __expf(v0.y - mx);
    e[2] = __expf(v0.z - mx); e[3] = __expf(v0.w - mx);
    e[4] = __expf(v1.x - mx); e[5] = __expf(v1.y - mx);
    e[6] = __expf(v1.z - mx); e[7] = __expf(v1.w - mx);
    float s8 = ((e[0] + e[1]) + (e[2] + e[3])) + ((e[4] + e[5]) + (e[6] + e[7]));

    red[t] = s8;
    __syncthreads();
    for (int s = 128; s > 0; s >>= 1) {
        if (t < s) red[t] += red[t + s];
        __syncthreads();
    }
    const float inv = 1.0f / red[0];

    unsigned short* pr = (unsigned short*)sr;
    ushort4 w0, w1;
    w0.x = f2bf(e[0] * inv); w0.y = f2bf(e[1] * inv);
    w0.z = f2bf(e[2] * inv); w0.w = f2bf(e[3] * inv);
    w1.x = f2bf(e[4] * inv); w1.y = f2bf(e[5] * inv);
    w1.z = f2bf(e[6] * inv); w1.w = f2bf(e[7] * inv);
    *(ushort4*)&pr[t * 8]     = w0;
    *(ushort4*)&pr[t * 8 + 4] = w1;
}

extern "C" void kernel_launch(void* const* d_in, const int* in_sizes, int n_in,
                              void* d_out, int out_size, void* d_ws, size_t ws_size,
                              hipStream_t stream)
{
    const float* x    = (const float*)d_in[0];
    const int*   mask = (const int*)d_in[1];
    const float* Wq   = (const float*)d_in[2];
    const float* bq   = (const float*)d_in[3];
    const float* Wk   = (const float*)d_in[4];
    const float* bk   = (const float*)d_in[5];
    const float* Wv   = (const float*)d_in[6];
    const float* bv   = (const float*)d_in[7];
    float* out = (float*)d_out;

    char* ws = (char*)d_ws;
    unsigned short* Q  = (unsigned short*)(ws);                  // [8][2048][1024] bf16, pre-scaled 1/32
    unsigned short* Kt = (unsigned short*)(ws + (32ull << 20));  // [8][2048][1024] bf16
    unsigned short* Vt = (unsigned short*)(ws + (64ull << 20));  // [8][1024][2048] bf16 (transposed)
    float*          Sm = (float*)(ws + (96ull << 20));           // [8][2048][2048] fp32 -> P bf16 in-place

    const int Mtot = 16384, D = 1024, S = 2048, B = 8;
    dim3 blk(256);

    // QKV projections: C = x @ W^T + b
    dim3 gp(Mtot / 128, D / 128, 1);
    gemm_bt<true, true, 0, false><<<gp, blk, 0, stream>>>(
        x, Wq, Q, bq, nullptr, Mtot, D, D, 1024, 1024, 1024, 0, 0, 0, 0.03125f);
    gemm_bt<true, true, 0, false><<<gp, blk, 0, stream>>>(
        x, Wk, Kt, bk, nullptr, Mtot, D, D, 1024, 1024, 1024, 0, 0, 0, 1.0f);
    gemm_bt<true, true, 0, true><<<gp, blk, 0, stream>>>(
        x, Wv, Vt, bv, nullptr, Mtot, D, D, 1024, 1024, 1024, 0, 0, 0, 1.0f);

    // scores: S_b = Q_b @ K_b^T  (scale already folded into Q), mask in epilogue
    dim3 gs(S / 128, S / 128, B);
    gemm_bt<false, false, 1, false><<<gs, blk, 0, stream>>>(
        Q, Kt, Sm, nullptr, mask, S, S, D, 1024, 1024, 2048,
        (long)S * D, (long)S * D, (long)S * S, 1.0f);

    // softmax rows (fp32 in, bf16 P out in-place; P row stride = 4096 bf16 elems)
    softmax_rows<<<dim3(B * S), blk, 0, stream>>>(Sm);

    // out: O_b = P_b @ V_b = P_b . Vt_b^T
    dim3 go(S / 128, D / 128, B);
    gemm_bt<false, false, 2, false><<<go, blk, 0, stream>>>(
        Sm, Vt, out, nullptr, nullptr, S, D, S, 4096, 2048, 1024,
        (long)S * 4096, (long)D * S, (long)S * D, 1.0f);
}

// Round 2
// 424.966 us; speedup vs baseline: 2.1309x; 2.1309x over previous
//
#include <hip/hip_runtime.h>
#include <hip/hip_bf16.h>

#define NEG_INF -1000000000.0f

typedef __attribute__((ext_vector_type(8))) short bf16x8;
typedef __attribute__((ext_vector_type(4))) float f32x4;

__device__ __forceinline__ unsigned short f2bf(float f) {
    unsigned int u = __float_as_uint(f);
    u += 0x7FFFu + ((u >> 16) & 1u);
    return (unsigned short)(u >> 16);
}

#define GLOAD_LDS16(gp, lp)                                                     \
    __builtin_amdgcn_global_load_lds(                                           \
        (const __attribute__((address_space(1))) void*)(gp),                    \
        (__attribute__((address_space(3))) void*)(lp), 16, 0, 0)

// BT-form bf16 GEMM: C[m][n] = sum_k A[m][k] * B[n][k]
// m97 structure: 128x128 tile, BK=64, 4 waves (2x2 of 64x64), linear LDS,
// global_load_lds width=16 staging, 2-barrier K-loop.
// EPI: 0 = projection (bf16 out, +bias, *scale, optional transposed store)
//      1 = scores (fp32 out, mask applied per column)
//      2 = plain fp32 out
template<int EPI, bool TRANS>
__global__ __launch_bounds__(256)
void gemm_bt(const unsigned short* __restrict__ A, const unsigned short* __restrict__ B,
             void* __restrict__ Cp, const float* __restrict__ bias,
             const int* __restrict__ mask,
             int K, long lda, long ldb, long ldc,
             long batchA, long batchB, long batchC, float scale)
{
    __shared__ unsigned short As[128 * 64];
    __shared__ unsigned short Bs[128 * 64];

    const int t    = threadIdx.x;
    const int lane = t & 63;
    const int w    = t >> 6;
    const int bm   = blockIdx.x * 128;
    const int bn   = blockIdx.y * 128;
    const int bz   = blockIdx.z;

    const int wm  = (w >> 1) * 64;
    const int wn  = (w & 1) * 64;
    const int lr  = lane & 15;
    const int lk8 = (lane >> 4) * 8;

    const size_t aoff = (size_t)bz * (size_t)batchA;
    const size_t boff = (size_t)bz * (size_t)batchB;
    const size_t coff = (size_t)bz * (size_t)batchC;

    // staging: wave w owns chunks [w*4, w*4+4); chunk = 8 rows x 64 cols = 1024B
    // lane l -> row (l>>3) within chunk, col elems (l&7)*8 (16B)
    const int ch0  = w * 4;
    const int srow = lane >> 3;
    const int scol = (lane & 7) * 8;

    const unsigned short* Abase = A + aoff + (size_t)(bm + ch0 * 8 + srow) * lda + scol;
    const unsigned short* Bbase = B + boff + (size_t)(bn + ch0 * 8 + srow) * ldb + scol;

    f32x4 acc[4][4];
#pragma unroll
    for (int i = 0; i < 4; ++i)
#pragma unroll
        for (int j = 0; j < 4; ++j)
            acc[i][j] = f32x4{0.f, 0.f, 0.f, 0.f};

    for (int kt = 0; kt < K; kt += 64) {
#pragma unroll
        for (int c = 0; c < 4; ++c) {
            GLOAD_LDS16(Abase + (size_t)c * 8 * lda + kt, &As[(ch0 + c) * 512]);
            GLOAD_LDS16(Bbase + (size_t)c * 8 * ldb + kt, &Bs[(ch0 + c) * 512]);
        }
        __syncthreads();

#pragma unroll
        for (int kk = 0; kk < 2; ++kk) {
            bf16x8 af[4], bfr[4];
#pragma unroll
            for (int i = 0; i < 4; ++i)
                af[i] = *(const bf16x8*)&As[(wm + i * 16 + lr) * 64 + kk * 32 + lk8];
#pragma unroll
            for (int j = 0; j < 4; ++j)
                bfr[j] = *(const bf16x8*)&Bs[(wn + j * 16 + lr) * 64 + kk * 32 + lk8];
#pragma unroll
            for (int i = 0; i < 4; ++i)
#pragma unroll
                for (int j = 0; j < 4; ++j)
                    acc[i][j] = __builtin_amdgcn_mfma_f32_16x16x32_bf16(af[i], bfr[j], acc[i][j], 0, 0, 0);
        }
        __syncthreads();
    }

    // ---- epilogue ----  C/D layout: col = lane&15, row = (lane>>4)*4 + reg
    const int r0 = (lane >> 4) * 4;
#pragma unroll
    for (int i = 0; i < 4; ++i) {
#pragma unroll
        for (int j = 0; j < 4; ++j) {
            const int gcol = bn + wn + j * 16 + lr;
            if (EPI == 0) {
                const float bv = bias[gcol];
                if (TRANS) {
                    // store transposed: C_t[b][n][s], m = b*2048 + s
                    const int m0 = bm + wm + i * 16 + r0;
                    const int bb = m0 >> 11;
                    const int s0 = m0 & 2047;
                    ushort4 wv;
                    wv.x = f2bf((acc[i][j][0] + bv) * scale);
                    wv.y = f2bf((acc[i][j][1] + bv) * scale);
                    wv.z = f2bf((acc[i][j][2] + bv) * scale);
                    wv.w = f2bf((acc[i][j][3] + bv) * scale);
                    *(ushort4*)((unsigned short*)Cp + (size_t)bb * (1024 * 2048)
                                + (size_t)gcol * 2048 + s0) = wv;
                } else {
#pragma unroll
                    for (int r = 0; r < 4; ++r) {
                        const int grow = bm + wm + i * 16 + r0 + r;
                        ((unsigned short*)Cp)[(size_t)grow * ldc + gcol] =
                            f2bf((acc[i][j][r] + bv) * scale);
                    }
                }
            } else if (EPI == 1) {
                const int mv = mask[(size_t)bz * 2048 + gcol];
#pragma unroll
                for (int r = 0; r < 4; ++r) {
                    const int grow = bm + wm + i * 16 + r0 + r;
                    float v = acc[i][j][r];
                    if (mv == 0) v = NEG_INF;
                    ((float*)Cp)[coff + (size_t)grow * ldc + gcol] = v;
                }
            } else {
#pragma unroll
                for (int r = 0; r < 4; ++r) {
                    const int grow = bm + wm + i * 16 + r0 + r;
                    ((float*)Cp)[coff + (size_t)grow * ldc + gcol] = acc[i][j][r];
                }
            }
        }
    }
}

// fp32 -> bf16 conversion, 4 elems/thread (n must be a multiple of 4)
__global__ __launch_bounds__(256)
void conv_f32_bf16(const float4* __restrict__ src, ushort4* __restrict__ dst, int n4)
{
    const int i = blockIdx.x * 256 + threadIdx.x;
    if (i < n4) {
        const float4 v = src[i];
        ushort4 wv;
        wv.x = f2bf(v.x); wv.y = f2bf(v.y); wv.z = f2bf(v.z); wv.w = f2bf(v.w);
        dst[i] = wv;
    }
}

// Row softmax over 2048 fp32 scores; writes P as bf16 in-place into the low
// half of the row's storage (row byte stride stays 8192 B -> 4096 bf16 elems).
__global__ __launch_bounds__(256)
void softmax_rows(float* __restrict__ S)
{
    const size_t row = blockIdx.x;
    float* sr = S + row * 2048;
    const int t = threadIdx.x;

    const float4 v0 = *(const float4*)&sr[t * 8];
    const float4 v1 = *(const float4*)&sr[t * 8 + 4];

    float m = fmaxf(fmaxf(fmaxf(v0.x, v0.y), fmaxf(v0.z, v0.w)),
                    fmaxf(fmaxf(v1.x, v1.y), fmaxf(v1.z, v1.w)));

    __shared__ float red[256];
    red[t] = m;
    __syncthreads();
    for (int s = 128; s > 0; s >>= 1) {
        if (t < s) red[t] = fmaxf(red[t], red[t + s]);
        __syncthreads();
    }
    const float mx = red[0];
    __syncthreads();

    float e[8];
    e[0] = __expf(v0.x - mx); e[1] = __expf(v0.y - mx);
    e[2] = __expf(v0.z - mx); e[3] = __expf(v0.w - mx);
    e[4] = __expf(v1.x - mx); e[5] = __expf(v1.y - mx);
    e[6] = __expf(v1.z - mx); e[7] = __expf(v1.w - mx);
    float s8 = ((e[0] + e[1]) + (e[2] + e[3])) + ((e[4] + e[5]) + (e[6] + e[7]));

    red[t] = s8;
    __syncthreads();
    for (int s = 128; s > 0; s >>= 1) {
        if (t < s) red[t] += red[t + s];
        __syncthreads();
    }
    const float inv = 1.0f / red[0];

    unsigned short* pr = (unsigned short*)sr;
    ushort4 w0, w1;
    w0.x = f2bf(e[0] * inv); w0.y = f2bf(e[1] * inv);
    w0.z = f2bf(e[2] * inv); w0.w = f2bf(e[3] * inv);
    w1.x = f2bf(e[4] * inv); w1.y = f2bf(e[5] * inv);
    w1.z = f2bf(e[6] * inv); w1.w = f2bf(e[7] * inv);
    *(ushort4*)&pr[t * 8]     = w0;
    *(ushort4*)&pr[t * 8 + 4] = w1;
}

extern "C" void kernel_launch(void* const* d_in, const int* in_sizes, int n_in,
                              void* d_out, int out_size, void* d_ws, size_t ws_size,
                              hipStream_t stream)
{
    const float* x    = (const float*)d_in[0];
    const int*   mask = (const int*)d_in[1];
    const float* Wq   = (const float*)d_in[2];
    const float* bq   = (const float*)d_in[3];
    const float* Wk   = (const float*)d_in[4];
    const float* bk   = (const float*)d_in[5];
    const float* Wv   = (const float*)d_in[6];
    const float* bv   = (const float*)d_in[7];
    float* out = (float*)d_out;

    char* ws = (char*)d_ws;
    unsigned short* Q  = (unsigned short*)(ws);                  // [8][2048][1024] bf16, pre-scaled 1/32
    unsigned short* Kt = (unsigned short*)(ws + (32ull << 20));  // [8][2048][1024] bf16
    unsigned short* Vt = (unsigned short*)(ws + (64ull << 20));  // [8][1024][2048] bf16 (transposed)
    float*          Sm = (float*)(ws + (96ull << 20));           // [8][2048][2048] fp32 -> P bf16 in-place
    // xb/wb live inside the (not-yet-written) Sm region; dead once projections finish
    unsigned short* xb = (unsigned short*)(ws + (96ull << 20));  // [8][2048][1024] bf16 of x
    unsigned short* wb = (unsigned short*)(ws + (128ull << 20)); // [3][1024][1024] bf16 weights

    const int D = 1024, S = 2048, B = 8, Mtot = 16384;
    dim3 blk(256);

    // ---- fp32 -> bf16 conversions ----
    conv_f32_bf16<<<dim3((Mtot * D / 4) / 256), blk, 0, stream>>>((const float4*)x, (ushort4*)xb, Mtot * D / 4);
    conv_f32_bf16<<<dim3((D * D / 4) / 256), blk, 0, stream>>>((const float4*)Wq, (ushort4*)(wb + 0ull * D * D), D * D / 4);
    conv_f32_bf16<<<dim3((D * D / 4) / 256), blk, 0, stream>>>((const float4*)Wk, (ushort4*)(wb + 1ull * D * D), D * D / 4);
    conv_f32_bf16<<<dim3((D * D / 4) / 256), blk, 0, stream>>>((const float4*)Wv, (ushort4*)(wb + 2ull * D * D), D * D / 4);

    // ---- QKV projections: C = x @ W^T + b ----
    dim3 gp(Mtot / 128, D / 128, 1);
    gemm_bt<0, false><<<gp, blk, 0, stream>>>(
        xb, wb + 0ull * D * D, Q, bq, nullptr, D, 1024, 1024, 1024, 0, 0, 0, 0.03125f);
    gemm_bt<0, false><<<gp, blk, 0, stream>>>(
        xb, wb + 1ull * D * D, Kt, bk, nullptr, D, 1024, 1024, 1024, 0, 0, 0, 1.0f);
    gemm_bt<0, true><<<gp, blk, 0, stream>>>(
        xb, wb + 2ull * D * D, Vt, bv, nullptr, D, 1024, 1024, 1024, 0, 0, 0, 1.0f);

    // ---- scores: S_b = Q_b @ K_b^T (scale folded into Q), mask in epilogue ----
    dim3 gs(S / 128, S / 128, B);
    gemm_bt<1, false><<<gs, blk, 0, stream>>>(
        Q, Kt, Sm, nullptr, mask, D, 1024, 1024, 2048,
        (long)S * D, (long)S * D, (long)S * S, 1.0f);

    // ---- softmax rows (fp32 in, bf16 P out in-place; P row stride 4096) ----
    softmax_rows<<<dim3(B * S), blk, 0, stream>>>(Sm);

    // ---- out: O_b = P_b @ V_b = P_b . Vt_b^T ----
    dim3 go(S / 128, D / 128, B);
    gemm_bt<2, false><<<go, blk, 0, stream>>>(
        (const unsigned short*)Sm, Vt, out, nullptr, nullptr, S, 4096, 2048, 1024,
        (long)S * 4096, (long)D * S, (long)S * D, 1.0f);
}

// Round 3
// 308.152 us; speedup vs baseline: 2.9386x; 1.3791x over previous
//
#include <hip/hip_runtime.h>
#include <hip/hip_bf16.h>

#define NEG_INF -1000000000.0f

typedef __attribute__((ext_vector_type(8))) short bf16x8;
typedef __attribute__((ext_vector_type(4))) float f32x4;

__device__ __forceinline__ unsigned short f2bf(float f) {
    unsigned int u = __float_as_uint(f);
    u += 0x7FFFu + ((u >> 16) & 1u);
    return (unsigned short)(u >> 16);
}

#define GLOAD_LDS16(gp, lp)                                                  \
    __builtin_amdgcn_global_load_lds(                                        \
        (const __attribute__((address_space(1))) void*)(gp),                 \
        (__attribute__((address_space(3))) void*)(lp), 16, 0, 0)

// 256x256-tile BT-form bf16 GEMM, BK=64, 512 threads = 8 waves (2Mx4N),
// 4 phases per K-tile, double-buffered 128 KiB LDS, counted-vmcnt pipeline,
// T2 XOR swizzle (linear LDS dest + pre-swizzled global src + swizzled read).
// C[m][n] = sum_k A[m][k]*B[n][k].
// EPI: 0 = projection (bf16 out, +bias, *scale, optional transposed store)
//      1 = scores (fp32 out, mask per column)   2 = plain fp32 out
template<int EPI, bool TRANS>
__global__ __launch_bounds__(512, 2)
void gemm256(const unsigned short* __restrict__ A, const unsigned short* __restrict__ B,
             void* __restrict__ Cp, const float* __restrict__ bias,
             const int* __restrict__ mask,
             int K, long lda, long ldb, long ldc,
             long batchA, long batchB, long batchC, float scale,
             int gx, int gy)
{
    __shared__ unsigned short As[2][16384];
    __shared__ unsigned short Bs[2][16384];

    // T1: bijective XCD swizzle (all launches have nwg % 8 == 0)
    int bid = blockIdx.x;
    bid = (bid & 7) * ((int)gridDim.x >> 3) + (bid >> 3);
    const int gxy = gx * gy;
    const int bz  = bid / gxy;
    const int rem = bid - bz * gxy;
    const int tm  = rem / gy;
    const int bm  = tm * 256;
    const int bn  = (rem - tm * gy) * 256;

    const int t    = threadIdx.x;
    const int lane = t & 63;
    const int w    = t >> 6;
    const int wr   = w >> 2;          // wave row 0..1 (128 rows each)
    const int wc   = w & 3;           // wave col 0..3 (64 cols each)
    const int lr   = lane & 15;
    const int lkg  = lane >> 4;       // 0..3
    const int sx8  = (lr & 7) * 8;    // T2 read-side XOR (row parity, elems)
    const int e0   = (lkg * 8) ^ sx8; // kk=0 chunk; kk=1 is e0^32

    // staging: thread t -> row tr (of 64-row load region), swizzled col chunk
    const int tr  = t >> 3;
    const int tcs = ((t & 7) ^ (tr & 7)) * 8;    // pre-swizzled source col (elems)
    const int wb512 = w * 512;                   // wave-uniform LDS elem offset

    const unsigned short* Ab = A + (size_t)bz * (size_t)batchA + (size_t)(bm + tr) * lda + tcs;
    const unsigned short* Bb = B + (size_t)bz * (size_t)batchB + (size_t)(bn + tr) * ldb + tcs;

#define ST_A(nb, L, kt) GLOAD_LDS16(Ab + (size_t)(L) * 64 * lda + (kt), &As[nb][(L) * 4096 + wb512])
#define ST_B(nb, L, kt) GLOAD_LDS16(Bb + (size_t)(L) * 64 * ldb + (kt), &Bs[nb][(L) * 4096 + wb512])

    f32x4 acc[8][4];
#pragma unroll
    for (int i = 0; i < 8; ++i)
#pragma unroll
        for (int j = 0; j < 4; ++j)
            acc[i][j] = f32x4{0.f, 0.f, 0.f, 0.f};

    // ---- prologue: stage tile 0 (needed-first order), wait all but A1,A3 ----
    ST_B(0, 0, 0); ST_B(0, 1, 0); ST_B(0, 2, 0); ST_B(0, 3, 0);
    ST_A(0, 0, 0); ST_A(0, 2, 0); ST_A(0, 1, 0); ST_A(0, 3, 0);
    asm volatile("s_waitcnt vmcnt(2)" ::: "memory");
    __builtin_amdgcn_s_barrier();

    bf16x8 a[2][2], b[4][2];

#define LOAD_A(BUF, qp)                                                      \
    _Pragma("unroll") for (int i2 = 0; i2 < 2; ++i2) {                       \
        const int Ra = wr * 128 + (qp) * 32 + i2 * 16 + lr;                  \
        a[i2][0] = *(const bf16x8*)&As[BUF][Ra * 64 + e0];                   \
        a[i2][1] = *(const bf16x8*)&As[BUF][Ra * 64 + (e0 ^ 32)];            \
    }

#define MFMA_Q(qp)                                                           \
    __builtin_amdgcn_s_setprio(1);                                           \
    _Pragma("unroll") for (int kk = 0; kk < 2; ++kk)                         \
    _Pragma("unroll") for (int i2 = 0; i2 < 2; ++i2)                         \
    _Pragma("unroll") for (int j = 0; j < 4; ++j)                            \
        acc[(qp) * 2 + i2][j] = __builtin_amdgcn_mfma_f32_16x16x32_bf16(     \
            a[i2][kk], b[j][kk], acc[(qp) * 2 + i2][j], 0, 0, 0);            \
    __builtin_amdgcn_s_setprio(0);

#define TILE(BUF, STAGE, ktn)                                                \
    {                                                                        \
        const int buf_ = (BUF); const int nb_ = buf_ ^ 1;                    \
        /* phase 0: B-frags (whole tile) + A quad 0; stage B0,B1 of next */  \
        _Pragma("unroll") for (int j = 0; j < 4; ++j) {                      \
            const int Rb = wc * 64 + j * 16 + lr;                            \
            b[j][0] = *(const bf16x8*)&Bs[buf_][Rb * 64 + e0];               \
            b[j][1] = *(const bf16x8*)&Bs[buf_][Rb * 64 + (e0 ^ 32)];        \
        }                                                                    \
        LOAD_A(buf_, 0)                                                      \
        if (STAGE) { ST_B(nb_, 0, ktn); ST_B(nb_, 1, ktn); }                 \
        __builtin_amdgcn_s_barrier();                                        \
        MFMA_Q(0)                                                            \
        __builtin_amdgcn_s_barrier();                                        \
        /* phase 1 */                                                        \
        LOAD_A(buf_, 1)                                                      \
        if (STAGE) { ST_B(nb_, 2, ktn); ST_B(nb_, 3, ktn); }                 \
        __builtin_amdgcn_s_barrier();                                        \
        MFMA_Q(1)                                                            \
        if (STAGE) { asm volatile("s_waitcnt vmcnt(4)" ::: "memory"); }      \
        else       { asm volatile("s_waitcnt vmcnt(0)" ::: "memory"); }      \
        __builtin_amdgcn_s_barrier();                                        \
        /* phase 2 */                                                        \
        LOAD_A(buf_, 2)                                                      \
        if (STAGE) { ST_A(nb_, 0, ktn); ST_A(nb_, 2, ktn); }                 \
        __builtin_amdgcn_s_barrier();                                        \
        MFMA_Q(2)                                                            \
        __builtin_amdgcn_s_barrier();                                        \
        /* phase 3 */                                                        \
        LOAD_A(buf_, 3)                                                      \
        if (STAGE) { ST_A(nb_, 1, ktn); ST_A(nb_, 3, ktn); }                 \
        __builtin_amdgcn_s_barrier();                                        \
        MFMA_Q(3)                                                            \
        if (STAGE) { asm volatile("s_waitcnt vmcnt(2)" ::: "memory"); }      \
        __builtin_amdgcn_s_barrier();                                        \
    }

    const int NT = K >> 6;
    for (int k = 0; k < NT - 1; ++k) {
        TILE(k & 1, true, (k + 1) << 6);
    }
    TILE((NT - 1) & 1, false, 0);

#undef TILE
#undef MFMA_Q
#undef LOAD_A
#undef ST_A
#undef ST_B

    // ---- epilogue ----  C/D: col = lane&15 (lr), row = lkg*4 + reg
    const int r0 = lkg * 4;
    const size_t coff = (size_t)bz * (size_t)batchC;
#pragma unroll
    for (int ri = 0; ri < 8; ++ri) {
#pragma unroll
        for (int j = 0; j < 4; ++j) {
            const int gcol = bn + wc * 64 + j * 16 + lr;
            if (EPI == 0) {
                const float bv = bias[gcol];
                if (TRANS) {
                    const int m0 = bm + wr * 128 + ri * 16 + r0;
                    const int bb = m0 >> 11;
                    const int s0 = m0 & 2047;
                    ushort4 wv;
                    wv.x = f2bf((acc[ri][j][0] + bv) * scale);
                    wv.y = f2bf((acc[ri][j][1] + bv) * scale);
                    wv.z = f2bf((acc[ri][j][2] + bv) * scale);
                    wv.w = f2bf((acc[ri][j][3] + bv) * scale);
                    *(ushort4*)((unsigned short*)Cp + (size_t)bb * (1024 * 2048)
                                + (size_t)gcol * 2048 + s0) = wv;
                } else {
#pragma unroll
                    for (int r = 0; r < 4; ++r) {
                        const int grow = bm + wr * 128 + ri * 16 + r0 + r;
                        ((unsigned short*)Cp)[(size_t)grow * ldc + gcol] =
                            f2bf((acc[ri][j][r] + bv) * scale);
                    }
                }
            } else if (EPI == 1) {
                const int mv = mask[(size_t)bz * 2048 + gcol];
#pragma unroll
                for (int r = 0; r < 4; ++r) {
                    const int grow = bm + wr * 128 + ri * 16 + r0 + r;
                    float v = acc[ri][j][r];
                    if (mv == 0) v = NEG_INF;
                    ((float*)Cp)[coff + (size_t)grow * ldc + gcol] = v;
                }
            } else {
#pragma unroll
                for (int r = 0; r < 4; ++r) {
                    const int grow = bm + wr * 128 + ri * 16 + r0 + r;
                    ((float*)Cp)[coff + (size_t)grow * ldc + gcol] = acc[ri][j][r];
                }
            }
        }
    }
}

// fp32 -> bf16 conversion, 4 elems/thread
__global__ __launch_bounds__(256)
void conv_f32_bf16(const float4* __restrict__ src, ushort4* __restrict__ dst, int n4)
{
    const int i = blockIdx.x * 256 + threadIdx.x;
    if (i < n4) {
        const float4 v = src[i];
        ushort4 wv;
        wv.x = f2bf(v.x); wv.y = f2bf(v.y); wv.z = f2bf(v.z); wv.w = f2bf(v.w);
        dst[i] = wv;
    }
}

// Row softmax over 2048 fp32 scores; writes P as bf16 in-place into the low
// half of the row's storage (row stride stays 4096 bf16 elems).
__global__ __launch_bounds__(256)
void softmax_rows(float* __restrict__ S)
{
    const size_t row = blockIdx.x;
    float* sr = S + row * 2048;
    const int t = threadIdx.x;

    const float4 v0 = *(const float4*)&sr[t * 8];
    const float4 v1 = *(const float4*)&sr[t * 8 + 4];

    float m = fmaxf(fmaxf(fmaxf(v0.x, v0.y), fmaxf(v0.z, v0.w)),
                    fmaxf(fmaxf(v1.x, v1.y), fmaxf(v1.z, v1.w)));

    __shared__ float red[256];
    red[t] = m;
    __syncthreads();
    for (int s = 128; s > 0; s >>= 1) {
        if (t < s) red[t] = fmaxf(red[t], red[t + s]);
        __syncthreads();
    }
    const float mx = red[0];
    __syncthreads();

    float e[8];
    e[0] = __expf(v0.x - mx); e[1] = __expf(v0.y - mx);
    e[2] = __expf(v0.z - mx); e[3] = __expf(v0.w - mx);
    e[4] = __expf(v1.x - mx); e[5] = __expf(v1.y - mx);
    e[6] = __expf(v1.z - mx); e[7] = __expf(v1.w - mx);
    float s8 = ((e[0] + e[1]) + (e[2] + e[3])) + ((e[4] + e[5]) + (e[6] + e[7]));

    red[t] = s8;
    __syncthreads();
    for (int s = 128; s > 0; s >>= 1) {
        if (t < s) red[t] += red[t + s];
        __syncthreads();
    }
    const float inv = 1.0f / red[0];

    unsigned short* pr = (unsigned short*)sr;
    ushort4 w0, w1;
    w0.x = f2bf(e[0] * inv); w0.y = f2bf(e[1] * inv);
    w0.z = f2bf(e[2] * inv); w0.w = f2bf(e[3] * inv);
    w1.x = f2bf(e[4] * inv); w1.y = f2bf(e[5] * inv);
    w1.z = f2bf(e[6] * inv); w1.w = f2bf(e[7] * inv);
    *(ushort4*)&pr[t * 8]     = w0;
    *(ushort4*)&pr[t * 8 + 4] = w1;
}

extern "C" void kernel_launch(void* const* d_in, const int* in_sizes, int n_in,
                              void* d_out, int out_size, void* d_ws, size_t ws_size,
                              hipStream_t stream)
{
    const float* x    = (const float*)d_in[0];
    const int*   mask = (const int*)d_in[1];
    const float* Wq   = (const float*)d_in[2];
    const float* bq   = (const float*)d_in[3];
    const float* Wk   = (const float*)d_in[4];
    const float* bk   = (const float*)d_in[5];
    const float* Wv   = (const float*)d_in[6];
    const float* bv   = (const float*)d_in[7];
    float* out = (float*)d_out;

    char* ws = (char*)d_ws;
    unsigned short* Q  = (unsigned short*)(ws);                  // [8][2048][1024] bf16, pre-scaled 1/32
    unsigned short* Kt = (unsigned short*)(ws + (32ull << 20));  // [8][2048][1024] bf16
    unsigned short* Vt = (unsigned short*)(ws + (64ull << 20));  // [8][1024][2048] bf16 (transposed)
    float*          Sm = (float*)(ws + (96ull << 20));           // [8][2048][2048] fp32 -> P bf16 in-place
    unsigned short* xb = (unsigned short*)(ws + (96ull << 20));  // bf16 x (dead after projections)
    unsigned short* wb = (unsigned short*)(ws + (128ull << 20)); // bf16 weights

    const int D = 1024, S = 2048, B = 8, Mtot = 16384;
    dim3 blk2(256), blk5(512);

    // ---- fp32 -> bf16 conversions ----
    conv_f32_bf16<<<dim3((Mtot * D / 4) / 256), blk2, 0, stream>>>((const float4*)x, (ushort4*)xb, Mtot * D / 4);
    conv_f32_bf16<<<dim3((D * D / 4) / 256), blk2, 0, stream>>>((const float4*)Wq, (ushort4*)(wb + 0ull * D * D), D * D / 4);
    conv_f32_bf16<<<dim3((D * D / 4) / 256), blk2, 0, stream>>>((const float4*)Wk, (ushort4*)(wb + 1ull * D * D), D * D / 4);
    conv_f32_bf16<<<dim3((D * D / 4) / 256), blk2, 0, stream>>>((const float4*)Wv, (ushort4*)(wb + 2ull * D * D), D * D / 4);

    // ---- QKV projections: C = x @ W^T + b  (grid 64x4 = 256 blocks) ----
    gemm256<0, false><<<dim3(256), blk5, 0, stream>>>(
        xb, wb + 0ull * D * D, Q, bq, nullptr, D, 1024, 1024, 1024, 0, 0, 0, 0.03125f, 64, 4);
    gemm256<0, false><<<dim3(256), blk5, 0, stream>>>(
        xb, wb + 1ull * D * D, Kt, bk, nullptr, D, 1024, 1024, 1024, 0, 0, 0, 1.0f, 64, 4);
    gemm256<0, true><<<dim3(256), blk5, 0, stream>>>(
        xb, wb + 2ull * D * D, Vt, bv, nullptr, D, 1024, 1024, 1024, 0, 0, 0, 1.0f, 64, 4);

    // ---- scores: S_b = Q_b @ K_b^T (scale folded into Q), mask in epilogue ----
    gemm256<1, false><<<dim3(512), blk5, 0, stream>>>(
        Q, Kt, Sm, nullptr, mask, D, 1024, 1024, 2048,
        (long)S * D, (long)S * D, (long)S * S, 1.0f, 8, 8);

    // ---- softmax rows (fp32 in, bf16 P out in-place; P row stride 4096) ----
    softmax_rows<<<dim3(B * S), blk2, 0, stream>>>(Sm);

    // ---- out: O_b = P_b @ V_b = P_b . Vt_b^T ----
    gemm256<2, false><<<dim3(256), blk5, 0, stream>>>(
        (const unsigned short*)Sm, Vt, out, nullptr, nullptr, S, 4096, 2048, 1024,
        (long)S * 4096, (long)D * S, (long)S * D, 1.0f, 8, 4);
}